// Round 5
// baseline (170.526 us; speedup 1.0000x reference)
//
#include <hip/hip_runtime.h>
#include <stdint.h>

constexpr int Bq = 8, Nq = 2048, Mq = 2048, Dq = 256;
constexpr int TILE = 128;          // 128x128 output tile per block
constexpr int KC = 32;             // fp32 k per chunk == MFMA K
constexpr int NCH = Dq / KC;       // 8 chunks
constexpr int LDS_S = 40;          // fallback kernel: 80B row stride

typedef float f32x4 __attribute__((ext_vector_type(4)));
typedef _Float16 f16x8 __attribute__((ext_vector_type(8)));
typedef _Float16 f16x4 __attribute__((ext_vector_type(4)));
typedef __fp16 fp16x2 __attribute__((ext_vector_type(2)));  // cvt_pkrtz native type

__device__ __forceinline__ uint32_t f2sortable(float f) {
  uint32_t u = __float_as_uint(f);
  return (u & 0x80000000u) ? ~u : (u | 0x80000000u);
}
__device__ __forceinline__ float sortable2f(uint32_t s) {
  uint32_t u = (s & 0x80000000u) ? (s ^ 0x80000000u) : ~s;
  return __uint_as_float(u);
}

__device__ __forceinline__ void load16(float* d, const float* __restrict__ p) {
  *(float4*)&d[0]  = *(const float4*)(p + 0);
  *(float4*)&d[4]  = *(const float4*)(p + 4);
  *(float4*)&d[8]  = *(const float4*)(p + 8);
  *(float4*)&d[12] = *(const float4*)(p + 12);
}

// Truncation split: h = x with low 13 mantissa bits cleared (exactly f16-
// representable; residual x-h exact by Sterbenz). al kept UNSCALED so all
// three MFMA terms share one accumulator: a.b ~= ah.bh + ah.bl + al.bh.
// Dropped al.bl ~ 2^-21|a||b| -> sim error ~1e-8; f16-denorm loss on tiny
// al -> sim error < 5e-7. Both negligible vs mean argmax gap 0.013.
__device__ __forceinline__ void split8(const float* x, f16x8* hi, f16x8* lo,
                                       float& sq) {
  union { f16x8 v; fp16x2 p[4]; } H, L;
#pragma unroll
  for (int j = 0; j < 4; ++j) {
    float x0 = x[2 * j], x1 = x[2 * j + 1];
    sq = fmaf(x0, x0, sq);
    sq = fmaf(x1, x1, sq);
    float h0 = __uint_as_float(__float_as_uint(x0) & 0xFFFFE000u);
    float h1 = __uint_as_float(__float_as_uint(x1) & 0xFFFFE000u);
    H.p[j] = __builtin_amdgcn_cvt_pkrtz(h0, h1);          // exact (13-bit mantissa)
    L.p[j] = __builtin_amdgcn_cvt_pkrtz(x0 - h0, x1 - h1); // RTZ on residual: fine
  }
  *hi = H.v;
  *lo = L.v;
}

// ---------------------------------------------------------------------------
// Preprocess fp32 -> chunked f16 hi/lo + inv-norms. Layout X[b][chunk][row][32]
// f16 (64 B rows): a (tile,chunk) slab of 128 rows is 8 KB CONTIGUOUS ->
// global_load_lds width-16 with linear LDS destination; per-wave A-fragment
// tiles (16 rows x 64 B) are contiguous 1 KB coalesced register loads.
// ---------------------------------------------------------------------------

__global__ __launch_bounds__(256)
void prep_kernel(const float* __restrict__ src, const float* __restrict__ dst,
                 _Float16* __restrict__ Ah, _Float16* __restrict__ Al,
                 _Float16* __restrict__ Bh, _Float16* __restrict__ Bl,
                 float* __restrict__ invnx, float* __restrict__ invny) {
  const int lane = threadIdx.x & 63;
  const int wv = threadIdx.x >> 6;
  const int r = blockIdx.x * 4 + wv;  // global row 0..16383 (one wave per row)

  const float* x;
  _Float16 *h, *l;
  float* inv;
  if (blockIdx.y == 0) { x = src; h = Ah; l = Al; inv = invnx; }
  else                 { x = dst; h = Bh; l = Bl; inv = invny; }

  // lane covers 4 consecutive k: coalesced 1 KB/wave read
  float4 v = *(const float4*)(x + (size_t)r * Dq + lane * 4);
  float sq = 0.f;
  union { f16x4 v; fp16x2 p[2]; } H, L;
  float e[4] = {v.x, v.y, v.z, v.w};
#pragma unroll
  for (int j = 0; j < 2; ++j) {
    float x0 = e[2 * j], x1 = e[2 * j + 1];
    sq = fmaf(x0, x0, sq);
    sq = fmaf(x1, x1, sq);
    float h0 = __uint_as_float(__float_as_uint(x0) & 0xFFFFE000u);
    float h1 = __uint_as_float(__float_as_uint(x1) & 0xFFFFE000u);
    H.p[j] = __builtin_amdgcn_cvt_pkrtz(h0, h1);
    L.p[j] = __builtin_amdgcn_cvt_pkrtz(x0 - h0, x1 - h1);
  }
#pragma unroll
  for (int m = 1; m <= 32; m <<= 1) sq += __shfl_xor(sq, m);

  const int b = r >> 11, row = r & 2047;
  const int c = lane >> 3, ko = (lane & 7) * 4;  // chunk, k-within-chunk
  size_t idx = ((size_t)(b * NCH + c) * 2048 + row) * KC + ko;
  *(f16x4*)&h[idx] = H.v;
  *(f16x4*)&l[idx] = L.v;
  if (lane == 0) inv[r] = 1.0f / sqrtf(sq);  // norms ~16; eps clamp never active
}

// ---------------------------------------------------------------------------
// Main kernel: B (hi/lo) staged through double-buffered LDS (32 KiB total),
// A (hi/lo) read global->register at use. Rationale (round-4 post-mortem):
// three different 2-blocks/CU schedules all plateaued at ~96 us / 22%
// MfmaUtil -> latency-bound from too few waves/SIMD, not any pipe. Halving
// LDS to 32 KiB + __launch_bounds__(256,4) (VGPR<=128) gives 4 blocks/CU =
// 4 waves/SIMD from desynced blocks; TLP fills the VMEM/ds_read latency
// holes. vmcnt is in-order: the counted wait before the first MFMA (A frags)
// also retires the earlier-issued B stage loads, so the barrier drain at the
// end of each chunk stays ~free.
// ---------------------------------------------------------------------------

constexpr size_t CSTR = (size_t)2048 * KC;  // chunk stride in elements

// wave w stages 4 KB of the 16 KB (Bh,Bl) chunk slab: arr = w>>1, half = w&1
__device__ __forceinline__ void stageB(const _Float16* g, _Float16* l, int lane) {
  const char* gc = (const char*)g + lane * 16;
  char* lc = (char*)l;
#pragma unroll
  for (int i = 0; i < 4; ++i)
    __builtin_amdgcn_global_load_lds(
        (const __attribute__((address_space(1))) void*)(gc + i * 1024),
        (__attribute__((address_space(3))) void*)(lc + i * 1024),
        16, 0, 0);
}

__global__ __launch_bounds__(256, 4)
void simmax_mfma(const _Float16* __restrict__ Ah, const _Float16* __restrict__ Al,
                 const _Float16* __restrict__ Bh, const _Float16* __restrict__ Bl,
                 const float* __restrict__ invnx, const float* __restrict__ invny,
                 unsigned long long* __restrict__ best) {
  // [buf][Bh/Bl][row][k] = 32 KiB -> 4 blocks/CU (16 waves/CU)
  __shared__ __align__(16) _Float16 lds[2][2][TILE][KC];

  // T1 XCD swizzle (bijective: 2048 % 8 == 0). XCD k owns the 256 tiles of
  // b=k: per-XCD working set = A(b)+B(b) = 4 MB = one L2. Validated round 2:
  // FETCH_SIZE 74 -> 16.6 MB.
  const int orig = blockIdx.x;
  const int logical = (orig & 7) * 256 + (orig >> 3);
  const int b = logical >> 8;
  const int nt = (logical >> 4) & 15;
  const int mt = logical & 15;

  const int tid = threadIdx.x;
  const int lane = tid & 63;
  const int wave = tid >> 6;
  const int wy = wave >> 1, wx = wave & 1;  // wave tile: rows wy*64, cols wx*64
  const int ln15 = lane & 15, lq = lane >> 4;

  // B staging: wave w covers 4 KB (2048 f16) of the 16 KB (Bh,Bl) chunk slab
  const _Float16* gB0 = ((wave >> 1) == 0 ? Bh : Bl) +
      ((size_t)(b * NCH) * 2048 + mt * TILE) * KC + (wave & 1) * 2048;
  _Float16* ldsW0 = &lds[0][wave >> 1][0][0] + (wave & 1) * 2048;
  _Float16* ldsW1 = &lds[1][wave >> 1][0][0] + (wave & 1) * 2048;

  // A fragment base (per-lane): rows nt*TILE + wy*64 + rt*16 + ln15, k-half lq
  const size_t rbA =
      ((size_t)(b * NCH) * 2048 + nt * TILE + wy * 64 + ln15) * KC + lq * 8;
  const _Float16* pAh = Ah + rbA;
  const _Float16* pAl = Al + rbA;

  f32x4 acc[4][4];
#pragma unroll
  for (int i = 0; i < 4; ++i)
#pragma unroll
    for (int j = 0; j < 4; ++j) acc[i][j] = (f32x4){0.f, 0.f, 0.f, 0.f};

  stageB(gB0, ldsW0, lane);
  __syncthreads();  // buf0 ready

#pragma unroll 2
  for (int c = 0; c < NCH; ++c) {
    const int cb = c & 1;
    // 1) issue next-chunk B stage first (in-order vmcnt: retired by the
    //    A-load wait below; overwrites lds[cb^1], published at the barrier)
    if (c + 1 < NCH)
      stageB(gB0 + (size_t)(c + 1) * CSTR, (cb ? ldsW0 : ldsW1), lane);

    // 2) A fragments global->reg at use (1 KB coalesced per tile, L2-hot;
    //    latency covered by 4 waves/SIMD TLP)
    f16x8 ahf[4], alf[4];
#pragma unroll
    for (int rt = 0; rt < 4; ++rt) {
      const size_t o = (size_t)c * CSTR + (size_t)rt * 16 * KC;
      ahf[rt] = *(const f16x8*)(pAh + o);
      alf[rt] = *(const f16x8*)(pAl + o);
    }

    // 3) B fragments from LDS: [row = lane&15][k = (lane>>4)*8 + j]
    f16x8 bhf[4], blf[4];
#pragma unroll
    for (int ct = 0; ct < 4; ++ct) {
      const int rb = wx * 64 + ct * 16 + ln15;
      bhf[ct] = *(const f16x8*)&lds[cb][0][rb][lq * 8];
      blf[ct] = *(const f16x8*)&lds[cb][1][rb][lq * 8];
    }

    // 4) 48 MFMAs
#pragma unroll
    for (int rt = 0; rt < 4; ++rt) {
#pragma unroll
      for (int ct = 0; ct < 4; ++ct) {
        acc[rt][ct] = __builtin_amdgcn_mfma_f32_16x16x32_f16(ahf[rt], bhf[ct], acc[rt][ct], 0, 0, 0);
        acc[rt][ct] = __builtin_amdgcn_mfma_f32_16x16x32_f16(ahf[rt], blf[ct], acc[rt][ct], 0, 0, 0);
        acc[rt][ct] = __builtin_amdgcn_mfma_f32_16x16x32_f16(alf[rt], bhf[ct], acc[rt][ct], 0, 0, 0);
      }
    }
    if (c + 1 < NCH) __syncthreads();  // publish staged buf, guard overwrite
  }

  // epilogue: norms from global (L2-hot)
  float invy[4];
#pragma unroll
  for (int ct = 0; ct < 4; ++ct)
    invy[ct] = invny[(size_t)b * Mq + mt * TILE + wx * 64 + ct * 16 + ln15];

  // C/D layout per 16x16 tile: col = lane&15, row = (lane>>4)*4 + reg
#pragma unroll
  for (int rt = 0; rt < 4; ++rt) {
#pragma unroll
    for (int reg = 0; reg < 4; ++reg) {
      float bq = -1e30f;
      int bc = 0x7FFFFFFF;
#pragma unroll
      for (int ct = 0; ct < 4; ++ct) {
        float q = acc[rt][ct][reg] * invy[ct];
        int cg = mt * TILE + wx * 64 + ct * 16 + ln15;
        if (q > bq || (q == bq && cg < bc)) { bq = q; bc = cg; }
      }
#pragma unroll
      for (int m = 1; m <= 8; m <<= 1) {
        float q2 = __shfl_xor(bq, m);
        int c2 = __shfl_xor(bc, m);
        if (q2 > bq || (q2 == bq && c2 < bc)) { bq = q2; bc = c2; }
      }
      if (ln15 == 0) {
        int rloc = wy * 64 + rt * 16 + lq * 4 + reg;
        float conf = bq * invnx[(size_t)b * Nq + nt * TILE + rloc];
        // signed-max key: (sortable^0x80000000)<<32 | ~idx. Monotone in conf,
        // tie -> smallest idx. 0xAA..AA poison is a more-negative i64 than any
        // real key, so NO memset pass is needed.
        unsigned long long p =
            ((unsigned long long)(f2sortable(conf) ^ 0x80000000u) << 32) |
            (uint32_t)(~(uint32_t)bc);
        atomicMax((long long*)&best[(size_t)b * Nq + nt * TILE + rloc],
                  (long long)p);
      }
    }
  }
}

// ---------------------------------------------------------------------------
// FALLBACK PATH (verbatim 90 us kernel) -- used if ws_size can't hold the
// 32.3 MiB preprocessed operands.
// ---------------------------------------------------------------------------
__global__ __launch_bounds__(256, 3)
void simmax_kernel(const float* __restrict__ src, const float* __restrict__ dst,
                   unsigned long long* __restrict__ best) {
  __shared__ _Float16 Ah[TILE][LDS_S], Al[TILE][LDS_S];
  __shared__ _Float16 Bh[TILE][LDS_S], Bl[TILE][LDS_S];
  __shared__ float invnx_s[TILE], invny_s[TILE];

  const int b = blockIdx.z, nt = blockIdx.y, mt = blockIdx.x;
  const int tid = threadIdx.x;
  const int lane = tid & 63;
  const int wave = tid >> 6;
  const int wy = wave >> 1, wx = wave & 1;
  const int ln15 = lane & 15, lq = lane >> 4;

  const int sr = tid >> 1;
  const int sk = (tid & 1) * 16;
  const float* Ag = src + ((size_t)(b * Nq + nt * TILE + sr)) * Dq + sk;
  const float* Bg = dst + ((size_t)(b * Mq + mt * TILE + sr)) * Dq + sk;

  f32x4 acc[4][4];
#pragma unroll
  for (int i = 0; i < 4; ++i)
#pragma unroll
    for (int j = 0; j < 4; ++j) acc[i][j] = (f32x4){0.f, 0.f, 0.f, 0.f};
  float sqa = 0.f, sqb = 0.f;

  float av[16], bv[16];
  load16(av, Ag);
  load16(bv, Bg);

  for (int c = 0; c < NCH; ++c) {
    f16x8 ah2[2], al2[2], bh2[2], bl2[2];
    split8(&av[0], &ah2[0], &al2[0], sqa);
    split8(&av[8], &ah2[1], &al2[1], sqa);
    split8(&bv[0], &bh2[0], &bl2[0], sqb);
    split8(&bv[8], &bh2[1], &bl2[1], sqb);
    __syncthreads();
    *(f16x8*)&Ah[sr][sk]     = ah2[0];
    *(f16x8*)&Ah[sr][sk + 8] = ah2[1];
    *(f16x8*)&Al[sr][sk]     = al2[0];
    *(f16x8*)&Al[sr][sk + 8] = al2[1];
    *(f16x8*)&Bh[sr][sk]     = bh2[0];
    *(f16x8*)&Bh[sr][sk + 8] = bh2[1];
    *(f16x8*)&Bl[sr][sk]     = bl2[0];
    *(f16x8*)&Bl[sr][sk + 8] = bl2[1];
    __syncthreads();

    if (c + 1 < NCH) {
      load16(av, Ag + (c + 1) * KC);
      load16(bv, Bg + (c + 1) * KC);
    }

    f16x8 bhf[4], blf[4];
#pragma unroll
    for (int ct = 0; ct < 4; ++ct) {
      int rowb = wx * 64 + ct * 16 + ln15;
      bhf[ct] = *(const f16x8*)&Bh[rowb][lq * 8];
      blf[ct] = *(const f16x8*)&Bl[rowb][lq * 8];
    }
#pragma unroll
    for (int rt = 0; rt < 4; ++rt) {
      int rowa = wy * 64 + rt * 16 + ln15;
      f16x8 ahf = *(const f16x8*)&Ah[rowa][lq * 8];
      f16x8 alf = *(const f16x8*)&Al[rowa][lq * 8];
#pragma unroll
      for (int ct = 0; ct < 4; ++ct) {
        acc[rt][ct] = __builtin_amdgcn_mfma_f32_16x16x32_f16(ahf, bhf[ct], acc[rt][ct], 0, 0, 0);
        acc[rt][ct] = __builtin_amdgcn_mfma_f32_16x16x32_f16(ahf, blf[ct], acc[rt][ct], 0, 0, 0);
        acc[rt][ct] = __builtin_amdgcn_mfma_f32_16x16x32_f16(alf, bhf[ct], acc[rt][ct], 0, 0, 0);
      }
    }
  }

  sqa += __shfl_xor(sqa, 1);
  sqb += __shfl_xor(sqb, 1);
  if ((tid & 1) == 0) {
    invnx_s[sr] = 1.0f / sqrtf(sqa);
    invny_s[sr] = 1.0f / sqrtf(sqb);
  }
  __syncthreads();

  float invny[4];
#pragma unroll
  for (int ct = 0; ct < 4; ++ct) invny[ct] = invny_s[wx * 64 + ct * 16 + ln15];

#pragma unroll
  for (int rt = 0; rt < 4; ++rt) {
#pragma unroll
    for (int reg = 0; reg < 4; ++reg) {
      float bq = -1e30f;
      int bc = 0x7FFFFFFF;
#pragma unroll
      for (int ct = 0; ct < 4; ++ct) {
        float q = acc[rt][ct][reg] * invny[ct];
        int cg = mt * TILE + wx * 64 + ct * 16 + ln15;
        if (q > bq || (q == bq && cg < bc)) { bq = q; bc = cg; }
      }
#pragma unroll
      for (int m = 1; m <= 8; m <<= 1) {
        float q2 = __shfl_xor(bq, m);
        int c2 = __shfl_xor(bc, m);
        if (q2 > bq || (q2 == bq && c2 < bc)) { bq = q2; bc = c2; }
      }
      if (ln15 == 0) {
        int rloc = wy * 64 + rt * 16 + lq * 4 + reg;
        float conf = bq * invnx_s[rloc];
        unsigned long long p =
            ((unsigned long long)(f2sortable(conf) ^ 0x80000000u) << 32) |
            (uint32_t)(~(uint32_t)bc);
        atomicMax((long long*)&best[(size_t)b * Nq + nt * TILE + rloc],
                  (long long)p);
      }
    }
  }
}

__global__ void finalize_kernel(const unsigned long long* __restrict__ best,
                                const float* __restrict__ pts,
                                float* __restrict__ out) {
  int i = blockIdx.x * blockDim.x + threadIdx.x;
  if (i >= Bq * Nq) return;
  unsigned long long p = best[i];
  uint32_t s = (uint32_t)(p >> 32) ^ 0x80000000u;
  int idx = (int)(~(uint32_t)(p & 0xFFFFFFFFull));
  float conf = sortable2f(s);
  int b = i / Nq;
  const float* q = pts + ((size_t)b * Mq + (size_t)idx) * 2;
  out[(size_t)i * 2 + 0] = q[0];
  out[(size_t)i * 2 + 1] = q[1];
  out[(size_t)(Bq * Nq) * 2 + i] = conf;  // confidence block after matched pts
}

extern "C" void kernel_launch(void* const* d_in, const int* in_sizes, int n_in,
                              void* d_out, int out_size, void* d_ws, size_t ws_size,
                              hipStream_t stream) {
  const float* src = (const float*)d_in[0];
  const float* dst = (const float*)d_in[1];
  const float* pts = (const float*)d_in[2];
  float* out = (float*)d_out;

  unsigned long long* best = (unsigned long long*)d_ws;  // 16384 * 8 B

  constexpr size_t BEST_B = (size_t)Bq * Nq * 8;           // 128 KiB
  constexpr size_t HL_B   = (size_t)Bq * 2048 * Dq * 2;    // 8 MiB per array
  constexpr size_t INV_B  = (size_t)Bq * 2048 * 4;         // 64 KiB
  constexpr size_t NEED   = BEST_B + 4 * HL_B + 2 * INV_B; // ~32.3 MiB

  if (ws_size >= NEED) {
    uint8_t* w = (uint8_t*)d_ws + BEST_B;
    _Float16* Ah = (_Float16*)(w);
    _Float16* Al = (_Float16*)(w + 1 * HL_B);
    _Float16* Bh = (_Float16*)(w + 2 * HL_B);
    _Float16* Bl = (_Float16*)(w + 3 * HL_B);
    float* invnx = (float*)(w + 4 * HL_B);
    float* invny = (float*)(w + 4 * HL_B + INV_B);

    prep_kernel<<<dim3(4096, 2, 1), 256, 0, stream>>>(src, dst, Ah, Al, Bh, Bl,
                                                      invnx, invny);
    simmax_mfma<<<dim3(2048, 1, 1), 256, 0, stream>>>(Ah, Al, Bh, Bl,
                                                      invnx, invny, best);
  } else {
    simmax_kernel<<<dim3(Mq / TILE, Nq / TILE, Bq), 256, 0, stream>>>(src, dst,
                                                                      best);
  }
  {
    int blocks = (Bq * Nq + 255) / 256;
    finalize_kernel<<<blocks, 256, 0, stream>>>(best, pts, out);
  }
}

// Round 6
// 170.267 us; speedup vs baseline: 1.0015x; 1.0015x over previous
//
#include <hip/hip_runtime.h>
#include <stdint.h>

constexpr int Bq = 8, Nq = 2048, Mq = 2048, Dq = 256;
constexpr int TILE = 128;          // fallback kernel tile
constexpr int KC = 32;             // fp32 k per chunk == MFMA K
constexpr int NCH = Dq / KC;       // 8 chunks
constexpr int LDS_S = 40;          // fallback kernel: 80B row stride
constexpr int NKT = 12;            // virtual K-tiles (BK=64): 3 terms x 4

typedef float f32x4 __attribute__((ext_vector_type(4)));
typedef _Float16 f16x8 __attribute__((ext_vector_type(8)));
typedef _Float16 f16x4 __attribute__((ext_vector_type(4)));
typedef __fp16 fp16x2 __attribute__((ext_vector_type(2)));  // cvt_pkrtz native type

__device__ __forceinline__ uint32_t f2sortable(float f) {
  uint32_t u = __float_as_uint(f);
  return (u & 0x80000000u) ? ~u : (u | 0x80000000u);
}
__device__ __forceinline__ float sortable2f(uint32_t s) {
  uint32_t u = (s & 0x80000000u) ? (s ^ 0x80000000u) : ~s;
  return __uint_as_float(u);
}

__device__ __forceinline__ void load16(float* d, const float* __restrict__ p) {
  *(float4*)&d[0]  = *(const float4*)(p + 0);
  *(float4*)&d[4]  = *(const float4*)(p + 4);
  *(float4*)&d[8]  = *(const float4*)(p + 8);
  *(float4*)&d[12] = *(const float4*)(p + 12);
}

// Truncation split: h = x with low 13 mantissa bits cleared (exactly f16-
// representable; residual x-h exact by Sterbenz). a.b ~= ah.bh + ah.bl + al.bh.
// Dropped al.bl ~ 2^-21|a||b|; negligible vs mean argmax gap 0.013.
__device__ __forceinline__ void split8(const float* x, f16x8* hi, f16x8* lo,
                                       float& sq) {
  union { f16x8 v; fp16x2 p[4]; } H, L;
#pragma unroll
  for (int j = 0; j < 4; ++j) {
    float x0 = x[2 * j], x1 = x[2 * j + 1];
    sq = fmaf(x0, x0, sq);
    sq = fmaf(x1, x1, sq);
    float h0 = __uint_as_float(__float_as_uint(x0) & 0xFFFFE000u);
    float h1 = __uint_as_float(__float_as_uint(x1) & 0xFFFFE000u);
    H.p[j] = __builtin_amdgcn_cvt_pkrtz(h0, h1);
    L.p[j] = __builtin_amdgcn_cvt_pkrtz(x0 - h0, x1 - h1);
  }
  *hi = H.v;
  *lo = L.v;
}

// ---------------------------------------------------------------------------
// Preprocess fp32 -> chunked f16 hi/lo + inv-norms. Layout X[b][chunk][row][32]
// f16 (64 B rows): a 256-row (tile,chunk) slab is 16 KB CONTIGUOUS ->
// global_load_lds staging units.
// ---------------------------------------------------------------------------

__global__ __launch_bounds__(256)
void prep_kernel(const float* __restrict__ src, const float* __restrict__ dst,
                 _Float16* __restrict__ Ah, _Float16* __restrict__ Al,
                 _Float16* __restrict__ Bh, _Float16* __restrict__ Bl,
                 float* __restrict__ invnx, float* __restrict__ invny) {
  const int lane = threadIdx.x & 63;
  const int wv = threadIdx.x >> 6;
  const int r = blockIdx.x * 4 + wv;  // global row 0..16383 (one wave per row)

  const float* x;
  _Float16 *h, *l;
  float* inv;
  if (blockIdx.y == 0) { x = src; h = Ah; l = Al; inv = invnx; }
  else                 { x = dst; h = Bh; l = Bl; inv = invny; }

  float4 v = *(const float4*)(x + (size_t)r * Dq + lane * 4);
  float sq = 0.f;
  union { f16x4 v; fp16x2 p[2]; } H, L;
  float e[4] = {v.x, v.y, v.z, v.w};
#pragma unroll
  for (int j = 0; j < 2; ++j) {
    float x0 = e[2 * j], x1 = e[2 * j + 1];
    sq = fmaf(x0, x0, sq);
    sq = fmaf(x1, x1, sq);
    float h0 = __uint_as_float(__float_as_uint(x0) & 0xFFFFE000u);
    float h1 = __uint_as_float(__float_as_uint(x1) & 0xFFFFE000u);
    H.p[j] = __builtin_amdgcn_cvt_pkrtz(h0, h1);
    L.p[j] = __builtin_amdgcn_cvt_pkrtz(x0 - h0, x1 - h1);
  }
#pragma unroll
  for (int m = 1; m <= 32; m <<= 1) sq += __shfl_xor(sq, m);

  const int b = r >> 11, row = r & 2047;
  const int c = lane >> 3, ko = (lane & 7) * 4;
  size_t idx = ((size_t)(b * NCH + c) * 2048 + row) * KC + ko;
  *(f16x4*)&h[idx] = H.v;
  *(f16x4*)&l[idx] = L.v;
  if (lane == 0) inv[r] = 1.0f / sqrtf(sq);
}

// ---------------------------------------------------------------------------
// MAIN: 256x256-tile 8-phase GEMM over virtual K = 768 ([Ah|Ah|Al].[Bh|Bl|Bh]
// concat -> per-K-tile operand-pointer select; one accumulator). Full
// T2+T3+T4+T5 stack:
//  - 8-slot LDS ring (16 KB units: {A,B} x {k-half}), stage 1 unit/phase,
//    2 gload_lds/wave/phase, unit staged 3-4 phases before first read.
//  - counted s_waitcnt vmcnt(4) at END of odd phases only (retires 2-4-phase
//    old loads; never drains recent ones). Dummy stage at last K-tile keeps
//    the wait uniform. Raw s_barrier (NOT __syncthreads -> no vmcnt(0)).
//  - XOR swizzle on ds_read col (2-way conflict = free) with pre-swizzled
//    gload source (both-sides involution, rule #21); swizzle reduces to a
//    per-lane constant qcol.
//  - s_setprio(1) around each 16-MFMA cluster (T5, gated on phase split).
// ---------------------------------------------------------------------------

__global__ __launch_bounds__(512, 2)
void simmax_8p(const _Float16* __restrict__ Ah, const _Float16* __restrict__ Al,
               const _Float16* __restrict__ Bh, const _Float16* __restrict__ Bl,
               const float* __restrict__ invnx, const float* __restrict__ invny,
               unsigned long long* __restrict__ best) {
  __shared__ __align__(16) _Float16 ring[8][256][KC];  // 128 KiB

  // XCD swizzle: 512 blocks = 8 XCDs x 64; XCD k owns batch b=k (A+B = 4 MB = 1 L2)
  const int orig = blockIdx.x;
  const int logical = (orig & 7) * 64 + (orig >> 3);
  const int b = logical >> 6;
  const int nt = (logical >> 3) & 7;
  const int mt = logical & 7;

  const int tid = threadIdx.x, lane = tid & 63, w = tid >> 6;
  const int wr = w >> 2, wc = w & 3;          // wave tile: rows wr*128, cols wc*64
  const int ln15 = lane & 15, lq = lane >> 4;
  const int qcol = (lq ^ ((ln15 >> 1) & 3)) * 8;  // swizzled 16B-granule col (elems)

  const size_t bBase = (size_t)b * (NCH * 2048 * KC);
  const size_t aRow = (size_t)(nt * 256) * KC;
  const size_t bRow = (size_t)(mt * 256) * KC;

  // staging per-lane source offset (swizzle pre-applied), elements.
  // wave stages granules U = w*128 + i*64 + lane of a 16 KB unit.
  const int U0 = w * 128 + lane;
  const int r0 = U0 >> 2, q0 = U0 & 3;
  const int so0 = r0 * KC + ((q0 ^ ((r0 >> 1) & 3)) << 3);  // +512 for i=1

  char* const ldsB = (char*)&ring[0][0][0];

  f32x4 acc[8][4];
#pragma unroll
  for (int i = 0; i < 8; ++i)
#pragma unroll
    for (int j = 0; j < 4; ++j) acc[i][j] = (f32x4){0.f, 0.f, 0.f, 0.f};
  f16x8 bf[4];

  // prologue: stage K-tile 0 (units 0..3: A-k0,B-k0,A-k1,B-k1) into group 0
#pragma unroll
  for (int u = 0; u < 4; ++u) {
    const _Float16* arr = (u & 1) ? Bh : Ah;
    const _Float16* src = arr + bBase + (size_t)(u >> 1) * 65536 +
                          ((u & 1) ? bRow : aRow) + so0;
    char* dst = ldsB + (size_t)u * 16384 + w * 2048;
    __builtin_amdgcn_global_load_lds(
        (const __attribute__((address_space(1))) void*)src,
        (__attribute__((address_space(3))) void*)dst, 16, 0, 0);
    __builtin_amdgcn_global_load_lds(
        (const __attribute__((address_space(1))) void*)(src + 512),
        (__attribute__((address_space(3))) void*)(dst + 1024), 16, 0, 0);
  }
  asm volatile("s_waitcnt vmcnt(4)" ::: "memory");  // k0 units retired, k1 in flight
  __builtin_amdgcn_s_barrier();

  // phase: { ds_read af (+bf if even) | stage unit Q of K-tile KT -> group RG^1 }
  //        barrier; lgkm(0); setprio1; 16 MFMA; setprio0; [vmcnt(4) if odd]; barrier
#define PHASE(Q, RG, KT)                                                        \
  do {                                                                          \
    constexpr int ks_ = (Q) >> 1, rt0_ = ((Q) & 1) * 4;                         \
    f16x8 af_[4];                                                               \
    _Pragma("unroll") for (int j = 0; j < 4; ++j)                               \
      af_[j] = *(const f16x8*)&ring[(RG) * 4 + ks_ * 2]                         \
          [wr * 128 + (rt0_ + j) * 16 + ln15][qcol];                            \
    if ((Q & 1) == 0) {                                                         \
      _Pragma("unroll") for (int ct = 0; ct < 4; ++ct)                          \
        bf[ct] = *(const f16x8*)&ring[(RG) * 4 + ks_ * 2 + 1]                   \
            [wc * 64 + ct * 16 + ln15][qcol];                                   \
    }                                                                           \
    {                                                                           \
      int kte_ = ((KT) < NKT) ? (KT) : 0; /* dummy restage keeps vmcnt uniform */\
      int tau_ = kte_ >> 2;                                                     \
      int c_ = 2 * (kte_ & 3) + ks_;                                            \
      const _Float16* arr_;                                                     \
      if ((Q) & 1) arr_ = (tau_ == 1) ? Bl : Bh;                                \
      else         arr_ = (tau_ == 2) ? Al : Ah;                                \
      const _Float16* src_ = arr_ + bBase + (size_t)c_ * 65536 +                \
                             (((Q) & 1) ? bRow : aRow) + so0;                   \
      char* dst_ = ldsB + (size_t)(((RG) ^ 1) * 4 + (Q)) * 16384 + w * 2048;    \
      __builtin_amdgcn_global_load_lds(                                         \
          (const __attribute__((address_space(1))) void*)src_,                  \
          (__attribute__((address_space(3))) void*)dst_, 16, 0, 0);             \
      __builtin_amdgcn_global_load_lds(                                         \
          (const __attribute__((address_space(1))) void*)(src_ + 512),          \
          (__attribute__((address_space(3))) void*)(dst_ + 1024), 16, 0, 0);    \
    }                                                                           \
    __builtin_amdgcn_s_barrier();                                               \
    asm volatile("s_waitcnt lgkmcnt(0)" ::: "memory");                          \
    __builtin_amdgcn_sched_barrier(0);                                          \
    __builtin_amdgcn_s_setprio(1);                                              \
    _Pragma("unroll") for (int j = 0; j < 4; ++j)                               \
      _Pragma("unroll") for (int ct = 0; ct < 4; ++ct)                          \
        acc[rt0_ + j][ct] = __builtin_amdgcn_mfma_f32_16x16x32_f16(             \
            af_[j], bf[ct], acc[rt0_ + j][ct], 0, 0, 0);                        \
    __builtin_amdgcn_s_setprio(0);                                              \
    if ((Q) & 1) asm volatile("s_waitcnt vmcnt(4)" ::: "memory");               \
    __builtin_amdgcn_s_barrier();                                               \
  } while (0)

#pragma unroll 1
  for (int tt = 0; tt < NKT; tt += 2) {
    PHASE(0, 0, tt + 1); PHASE(1, 0, tt + 1);
    PHASE(2, 0, tt + 1); PHASE(3, 0, tt + 1);
    PHASE(0, 1, tt + 2); PHASE(1, 1, tt + 2);
    PHASE(2, 1, tt + 2); PHASE(3, 1, tt + 2);
  }
#undef PHASE

  // epilogue: norms from global (L2-hot)
  float invy[4];
#pragma unroll
  for (int ct = 0; ct < 4; ++ct)
    invy[ct] = invny[(size_t)b * Mq + mt * 256 + wc * 64 + ct * 16 + ln15];
  const float* invxp = invnx + (size_t)b * Nq + nt * 256;

  // C/D layout per 16x16 tile: col = lane&15, row = (lane>>4)*4 + reg
#pragma unroll
  for (int rt = 0; rt < 8; ++rt) {
#pragma unroll
    for (int reg = 0; reg < 4; ++reg) {
      float bq = -1e30f;
      int bc = 0x7FFFFFFF;
#pragma unroll
      for (int ct = 0; ct < 4; ++ct) {
        float q = acc[rt][ct][reg] * invy[ct];
        int cg = mt * 256 + wc * 64 + ct * 16 + ln15;
        if (q > bq || (q == bq && cg < bc)) { bq = q; bc = cg; }
      }
#pragma unroll
      for (int m = 1; m <= 8; m <<= 1) {
        float q2 = __shfl_xor(bq, m);
        int c2 = __shfl_xor(bc, m);
        if (q2 > bq || (q2 == bq && c2 < bc)) { bq = q2; bc = c2; }
      }
      if (ln15 == 0) {
        int rloc = wr * 128 + rt * 16 + lq * 4 + reg;
        float conf = bq * invxp[rloc];
        unsigned long long p =
            ((unsigned long long)(f2sortable(conf) ^ 0x80000000u) << 32) |
            (uint32_t)(~(uint32_t)bc);
        atomicMax((long long*)&best[(size_t)b * Nq + nt * 256 + rloc],
                  (long long)p);
      }
    }
  }
}

// ---------------------------------------------------------------------------
// FALLBACK PATH (verbatim 90 us kernel) -- used if ws_size can't hold the
// 32.3 MiB preprocessed operands.
// ---------------------------------------------------------------------------
__global__ __launch_bounds__(256, 3)
void simmax_kernel(const float* __restrict__ src, const float* __restrict__ dst,
                   unsigned long long* __restrict__ best) {
  __shared__ _Float16 Ahs[TILE][LDS_S], Als[TILE][LDS_S];
  __shared__ _Float16 Bhs[TILE][LDS_S], Bls[TILE][LDS_S];
  __shared__ float invnx_s[TILE], invny_s[TILE];

  const int b = blockIdx.z, nt = blockIdx.y, mt = blockIdx.x;
  const int tid = threadIdx.x;
  const int lane = tid & 63;
  const int wave = tid >> 6;
  const int wy = wave >> 1, wx = wave & 1;
  const int ln15 = lane & 15, lq = lane >> 4;

  const int sr = tid >> 1;
  const int sk = (tid & 1) * 16;
  const float* Ag = src + ((size_t)(b * Nq + nt * TILE + sr)) * Dq + sk;
  const float* Bg = dst + ((size_t)(b * Mq + mt * TILE + sr)) * Dq + sk;

  f32x4 acc[4][4];
#pragma unroll
  for (int i = 0; i < 4; ++i)
#pragma unroll
    for (int j = 0; j < 4; ++j) acc[i][j] = (f32x4){0.f, 0.f, 0.f, 0.f};
  float sqa = 0.f, sqb = 0.f;

  float av[16], bv[16];
  load16(av, Ag);
  load16(bv, Bg);

  for (int c = 0; c < NCH; ++c) {
    f16x8 ah2[2], al2[2], bh2[2], bl2[2];
    split8(&av[0], &ah2[0], &al2[0], sqa);
    split8(&av[8], &ah2[1], &al2[1], sqa);
    split8(&bv[0], &bh2[0], &bl2[0], sqb);
    split8(&bv[8], &bh2[1], &bl2[1], sqb);
    __syncthreads();
    *(f16x8*)&Ahs[sr][sk]     = ah2[0];
    *(f16x8*)&Ahs[sr][sk + 8] = ah2[1];
    *(f16x8*)&Als[sr][sk]     = al2[0];
    *(f16x8*)&Als[sr][sk + 8] = al2[1];
    *(f16x8*)&Bhs[sr][sk]     = bh2[0];
    *(f16x8*)&Bhs[sr][sk + 8] = bh2[1];
    *(f16x8*)&Bls[sr][sk]     = bl2[0];
    *(f16x8*)&Bls[sr][sk + 8] = bl2[1];
    __syncthreads();

    if (c + 1 < NCH) {
      load16(av, Ag + (c + 1) * KC);
      load16(bv, Bg + (c + 1) * KC);
    }

    f16x8 bhf[4], blf[4];
#pragma unroll
    for (int ct = 0; ct < 4; ++ct) {
      int rowb = wx * 64 + ct * 16 + ln15;
      bhf[ct] = *(const f16x8*)&Bhs[rowb][lq * 8];
      blf[ct] = *(const f16x8*)&Bls[rowb][lq * 8];
    }
#pragma unroll
    for (int rt = 0; rt < 4; ++rt) {
      int rowa = wy * 64 + rt * 16 + ln15;
      f16x8 ahf = *(const f16x8*)&Ahs[rowa][lq * 8];
      f16x8 alf = *(const f16x8*)&Als[rowa][lq * 8];
#pragma unroll
      for (int ct = 0; ct < 4; ++ct) {
        acc[rt][ct] = __builtin_amdgcn_mfma_f32_16x16x32_f16(ahf, bhf[ct], acc[rt][ct], 0, 0, 0);
        acc[rt][ct] = __builtin_amdgcn_mfma_f32_16x16x32_f16(ahf, blf[ct], acc[rt][ct], 0, 0, 0);
        acc[rt][ct] = __builtin_amdgcn_mfma_f32_16x16x32_f16(alf, bhf[ct], acc[rt][ct], 0, 0, 0);
      }
    }
  }

  sqa += __shfl_xor(sqa, 1);
  sqb += __shfl_xor(sqb, 1);
  if ((tid & 1) == 0) {
    invnx_s[sr] = 1.0f / sqrtf(sqa);
    invny_s[sr] = 1.0f / sqrtf(sqb);
  }
  __syncthreads();

  float invny_r[4];
#pragma unroll
  for (int ct = 0; ct < 4; ++ct) invny_r[ct] = invny_s[wx * 64 + ct * 16 + ln15];

#pragma unroll
  for (int rt = 0; rt < 4; ++rt) {
#pragma unroll
    for (int reg = 0; reg < 4; ++reg) {
      float bq = -1e30f;
      int bc = 0x7FFFFFFF;
#pragma unroll
      for (int ct = 0; ct < 4; ++ct) {
        float q = acc[rt][ct][reg] * invny_r[ct];
        int cg = mt * TILE + wx * 64 + ct * 16 + ln15;
        if (q > bq || (q == bq && cg < bc)) { bq = q; bc = cg; }
      }
#pragma unroll
      for (int m = 1; m <= 8; m <<= 1) {
        float q2 = __shfl_xor(bq, m);
        int c2 = __shfl_xor(bc, m);
        if (q2 > bq || (q2 == bq && c2 < bc)) { bq = q2; bc = c2; }
      }
      if (ln15 == 0) {
        int rloc = wy * 64 + rt * 16 + lq * 4 + reg;
        float conf = bq * invnx_s[rloc];
        unsigned long long p =
            ((unsigned long long)(f2sortable(conf) ^ 0x80000000u) << 32) |
            (uint32_t)(~(uint32_t)bc);
        atomicMax((long long*)&best[(size_t)b * Nq + nt * TILE + rloc],
                  (long long)p);
      }
    }
  }
}

__global__ void finalize_kernel(const unsigned long long* __restrict__ best,
                                const float* __restrict__ pts,
                                float* __restrict__ out) {
  int i = blockIdx.x * blockDim.x + threadIdx.x;
  if (i >= Bq * Nq) return;
  unsigned long long p = best[i];
  uint32_t s = (uint32_t)(p >> 32) ^ 0x80000000u;
  int idx = (int)(~(uint32_t)(p & 0xFFFFFFFFull));
  float conf = sortable2f(s);
  int b = i / Nq;
  const float* q = pts + ((size_t)b * Mq + (size_t)idx) * 2;
  out[(size_t)i * 2 + 0] = q[0];
  out[(size_t)i * 2 + 1] = q[1];
  out[(size_t)(Bq * Nq) * 2 + i] = conf;  // confidence block after matched pts
}

extern "C" void kernel_launch(void* const* d_in, const int* in_sizes, int n_in,
                              void* d_out, int out_size, void* d_ws, size_t ws_size,
                              hipStream_t stream) {
  const float* src = (const float*)d_in[0];
  const float* dst = (const float*)d_in[1];
  const float* pts = (const float*)d_in[2];
  float* out = (float*)d_out;

  unsigned long long* best = (unsigned long long*)d_ws;  // 16384 * 8 B

  constexpr size_t BEST_B = (size_t)Bq * Nq * 8;           // 128 KiB
  constexpr size_t HL_B   = (size_t)Bq * 2048 * Dq * 2;    // 8 MiB per array
  constexpr size_t INV_B  = (size_t)Bq * 2048 * 4;         // 64 KiB
  constexpr size_t NEED   = BEST_B + 4 * HL_B + 2 * INV_B; // ~32.3 MiB

  if (ws_size >= NEED) {
    uint8_t* w = (uint8_t*)d_ws + BEST_B;
    _Float16* Ah = (_Float16*)(w);
    _Float16* Al = (_Float16*)(w + 1 * HL_B);
    _Float16* Bh = (_Float16*)(w + 2 * HL_B);
    _Float16* Bl = (_Float16*)(w + 3 * HL_B);
    float* invnx = (float*)(w + 4 * HL_B);
    float* invny = (float*)(w + 4 * HL_B + INV_B);

    prep_kernel<<<dim3(4096, 2, 1), 256, 0, stream>>>(src, dst, Ah, Al, Bh, Bl,
                                                      invnx, invny);
    simmax_8p<<<dim3(512, 1, 1), 512, 0, stream>>>(Ah, Al, Bh, Bl,
                                                   invnx, invny, best);
  } else {
    simmax_kernel<<<dim3(Mq / TILE, Nq / TILE, Bq), 256, 0, stream>>>(src, dst,
                                                                      best);
  }
  {
    int blocks = (Bq * Nq + 255) / 256;
    finalize_kernel<<<blocks, 256, 0, stream>>>(best, pts, out);
  }
}